// Round 1
// baseline (2638.241 us; speedup 1.0000x reference)
//
#include <hip/hip_runtime.h>
#include <math.h>

#define SB 32
#define SS 8192
#define SD 256
#define SH 512
#define CLIPV 3.0f

// ---------------------------------------------------------------------------
// K1: fused LayerNorm + two MLPs -> logits.  64 rows per block.
// LDS: XT[256][64] (64 KB, transposed normalized tile) + WB[64][64] (16 KB)
//  = 80 KB -> 2 blocks/CU.  Thread (tx,ty) owns rows 4*ty..+3, cols 4*tx..+3.
// Also writes per-row (mu, rstd) to ws for the weighted-sum pass.
// ---------------------------------------------------------------------------
__global__ __launch_bounds__(256, 2) void k_logits(
    const float* __restrict__ x,
    const float* __restrict__ gamma, const float* __restrict__ beta,
    const float* __restrict__ dw1, const float* __restrict__ db1,
    const float* __restrict__ dw2, const float* __restrict__ db2,
    const float* __restrict__ rw1, const float* __restrict__ rb1,
    const float* __restrict__ rw2, const float* __restrict__ rb2,
    float* __restrict__ logits, float* __restrict__ murstd)
{
    __shared__ float XT[SD][64];   // [k][row]
    __shared__ float WB[64][64];   // [kk][col]
    const int tid  = threadIdx.x;
    const int lane = tid & 63;
    const int wv   = tid >> 6;
    const size_t row0 = (size_t)blockIdx.x * 64;

    // ---- stage + LayerNorm: each wave handles 16 rows -----------------------
    const float4 gg = ((const float4*)gamma)[lane];
    const float4 bb = ((const float4*)beta)[lane];
    for (int rr = 0; rr < 16; ++rr) {
        const int r = wv * 16 + rr;
        const size_t row = row0 + (size_t)r;
        const float4 v = ((const float4*)(x + row * SD))[lane];
        float s = v.x + v.y + v.z + v.w;
        float q = v.x*v.x + v.y*v.y + v.z*v.z + v.w*v.w;
        #pragma unroll
        for (int off = 32; off; off >>= 1) {
            s += __shfl_xor(s, off);
            q += __shfl_xor(q, off);
        }
        const float mu   = s * (1.0f / SD);
        const float var  = q * (1.0f / SD) - mu * mu;
        const float rstd = rsqrtf(var + 1e-5f);
        if (lane == 0) { murstd[2*row] = mu; murstd[2*row+1] = rstd; }
        XT[lane*4+0][r] = (v.x - mu) * rstd * gg.x + bb.x;
        XT[lane*4+1][r] = (v.y - mu) * rstd * gg.y + bb.y;
        XT[lane*4+2][r] = (v.z - mu) * rstd * gg.z + bb.z;
        XT[lane*4+3][r] = (v.w - mu) * rstd * gg.w + bb.w;
    }

    const int tx = tid & 15;
    const int ty = tid >> 4;          // 0..15, rows 4*ty..4*ty+3
    float accD[4] = {0.f,0.f,0.f,0.f};
    float accR[4] = {0.f,0.f,0.f,0.f};

    for (int nc = 0; nc < 16; ++nc) {
        const float* __restrict__ W1 = (nc < 8) ? dw1 : rw1;
        const float* __restrict__ B1 = (nc < 8) ? db1 : rb1;
        const float* __restrict__ W2 = (nc < 8) ? dw2 : rw2;
        const int colb = (nc & 7) * 64;
        float acc[4][4] = {{0.f}};
        for (int kc = 0; kc < 4; ++kc) {
            __syncthreads();   // also covers XT-ready on first pass, WB reuse after
            #pragma unroll
            for (int i = 0; i < 4; ++i) {
                const int kk = i * 16 + ty;
                const float4 wv4 = *(const float4*)&W1[(size_t)(kc*64 + kk)*SH + colb + tx*4];
                *(float4*)&WB[kk][tx*4] = wv4;
            }
            __syncthreads();
            #pragma unroll
            for (int kk = 0; kk < 64; ++kk) {
                const float4 xa = *(const float4*)&XT[kc*64 + kk][ty*4];
                const float4 wa = *(const float4*)&WB[kk][tx*4];
                acc[0][0] = fmaf(xa.x, wa.x, acc[0][0]);
                acc[0][1] = fmaf(xa.x, wa.y, acc[0][1]);
                acc[0][2] = fmaf(xa.x, wa.z, acc[0][2]);
                acc[0][3] = fmaf(xa.x, wa.w, acc[0][3]);
                acc[1][0] = fmaf(xa.y, wa.x, acc[1][0]);
                acc[1][1] = fmaf(xa.y, wa.y, acc[1][1]);
                acc[1][2] = fmaf(xa.y, wa.z, acc[1][2]);
                acc[1][3] = fmaf(xa.y, wa.w, acc[1][3]);
                acc[2][0] = fmaf(xa.z, wa.x, acc[2][0]);
                acc[2][1] = fmaf(xa.z, wa.y, acc[2][1]);
                acc[2][2] = fmaf(xa.z, wa.z, acc[2][2]);
                acc[2][3] = fmaf(xa.z, wa.w, acc[2][3]);
                acc[3][0] = fmaf(xa.w, wa.x, acc[3][0]);
                acc[3][1] = fmaf(xa.w, wa.y, acc[3][1]);
                acc[3][2] = fmaf(xa.w, wa.z, acc[3][2]);
                acc[3][3] = fmaf(xa.w, wa.w, acc[3][3]);
            }
        }
        // epilogue for this 64-col chunk: bias + exact GELU + dot with w2
        #pragma unroll
        for (int i = 0; i < 4; ++i) {
            float sum = 0.f;
            #pragma unroll
            for (int j = 0; j < 4; ++j) {
                const int col = colb + tx*4 + j;
                const float h  = acc[i][j] + B1[col];
                const float ge = h * 0.5f * (1.0f + erff(h * 0.70710678118654752f));
                sum = fmaf(ge, W2[col], sum);
            }
            if (nc < 8) accD[i] += sum; else accR[i] += sum;
        }
    }

    // reduce partial dots across the 16 tx lanes (stays within the wave)
    #pragma unroll
    for (int m = 1; m <= 8; m <<= 1) {
        #pragma unroll
        for (int i = 0; i < 4; ++i) {
            accD[i] += __shfl_xor(accD[i], m);
            accR[i] += __shfl_xor(accR[i], m);
        }
    }
    if (tx == 0) {
        const float b2 = db2[0], r2 = rb2[0];
        #pragma unroll
        for (int i = 0; i < 4; ++i) {
            const float dr = accD[i] + b2;
            const float rs = accR[i] + r2;
            // softplus, numerically stable (matches jax.nn.softplus)
            const float sp = fmaxf(rs, 0.f) + log1pf(expf(-fabsf(rs)));
            float sc = dr - sp;                      // WARMUP_ETA=1, EML_BIAS=0
            sc = fminf(CLIPV, fmaxf(-CLIPV, sc));
            logits[row0 + (size_t)(ty*4 + i)] = sc;
        }
    }
}

// ---------------------------------------------------------------------------
// K2: per-batch masked softmax over S + stable top-3 (tie-break lowest index,
// matching jax.lax.top_k -- handles exact ties from the +/-3 clip).
// ---------------------------------------------------------------------------
__global__ __launch_bounds__(256) void k_softmax_topk(
    const float* __restrict__ logits, const int* __restrict__ mask,
    float* __restrict__ weights, float* __restrict__ ti, float* __restrict__ tw,
    float* __restrict__ flags)
{
    const int b = blockIdx.x, tid = threadIdx.x;
    const float* lg = logits + (size_t)b * SS;
    const int*   mk = mask   + (size_t)b * SS;
    float*       wt = weights + (size_t)b * SS;
    __shared__ float rv[4];
    __shared__ int   ri[4];
    __shared__ int   sCh[3];

    // masked max
    float mx = -INFINITY;
    for (int s = tid; s < SS; s += 256) if (mk[s]) mx = fmaxf(mx, lg[s]);
    #pragma unroll
    for (int off = 32; off; off >>= 1) mx = fmaxf(mx, __shfl_xor(mx, off));
    if ((tid & 63) == 0) rv[tid >> 6] = mx;
    __syncthreads();
    mx = fmaxf(fmaxf(rv[0], rv[1]), fmaxf(rv[2], rv[3]));
    __syncthreads();

    // masked sum of exp
    float sm = 0.f;
    for (int s = tid; s < SS; s += 256) if (mk[s]) sm += expf(lg[s] - mx);
    #pragma unroll
    for (int off = 32; off; off >>= 1) sm += __shfl_xor(sm, off);
    if ((tid & 63) == 0) rv[tid >> 6] = sm;
    __syncthreads();
    const float Z = rv[0] + rv[1] + rv[2] + rv[3];
    __syncthreads();
    const bool  any = (Z > 0.f) && (mx > -INFINITY);
    const float inv = any ? 1.0f / Z : 0.f;

    for (int s = tid; s < SS; s += 256) {
        const float w = (mk[s] && any) ? expf(lg[s] - mx) * inv : 0.f;
        wt[s] = w;
    }
    if (tid == 0) flags[b] = any ? 1.f : 0.f;
    __syncthreads();

    // top-3: 3 passes of block argmax with exclusion
    for (int t = 0; t < 3; ++t) {
        float bv = -1.f; int bi = 0;
        for (int s = tid; s < SS; s += 256) {
            bool ex = false;
            for (int u = 0; u < t; ++u) ex = ex || (s == sCh[u]);
            if (ex) continue;
            const float w = wt[s];
            if (w > bv || (w == bv && s < bi)) { bv = w; bi = s; }
        }
        #pragma unroll
        for (int off = 32; off; off >>= 1) {
            const float ov = __shfl_xor(bv, off);
            const int   oi = __shfl_xor(bi, off);
            if (ov > bv || (ov == bv && oi < bi)) { bv = ov; bi = oi; }
        }
        if ((tid & 63) == 0) { rv[tid >> 6] = bv; ri[tid >> 6] = bi; }
        __syncthreads();
        if (tid == 0) {
            for (int w2 = 1; w2 < 4; ++w2)
                if (rv[w2] > rv[0] || (rv[w2] == rv[0] && ri[w2] < ri[0])) { rv[0] = rv[w2]; ri[0] = ri[w2]; }
            sCh[t] = ri[0];
            ti[b*3 + t] = (float)ri[0];
            tw[b*3 + t] = rv[0];
        }
        __syncthreads();
    }
}

// ---------------------------------------------------------------------------
// K3: partial weighted sums  partial[b][c][d] = sum_{s in chunk} w * xhat[d]
// representation = (sum_s w_s * xhat_s) @ vw + vb * sum_w   (linearity)
// ---------------------------------------------------------------------------
__global__ __launch_bounds__(256) void k_wsum(
    const float* __restrict__ x, const float* __restrict__ weights,
    const float* __restrict__ murstd,
    const float* __restrict__ gamma, const float* __restrict__ beta,
    float* __restrict__ partials)
{
    const int c = blockIdx.x;          // 64 chunks of 128 rows
    const int b = blockIdx.y;
    const int d = threadIdx.x;         // 256 dims
    const float gg = gamma[d], bb = beta[d];
    float acc = 0.f;
    const size_t base = (size_t)b * SS + (size_t)c * 128;
    for (int s = 0; s < 128; ++s) {
        const size_t row = base + s;
        const float w = weights[row];          // uniform across block
        if (w != 0.f) {
            const float mu = murstd[2*row], rs = murstd[2*row+1];
            const float xv = x[row * SD + d];
            acc = fmaf(w, (xv - mu) * rs * gg + bb, acc);
        }
    }
    partials[((size_t)b * 64 + c) * SD + d] = acc;
}

// ---------------------------------------------------------------------------
// K4: reduce partials, then rep[b] = svec @ vw + vb * anyMask
// ---------------------------------------------------------------------------
__global__ __launch_bounds__(256) void k_final(
    const float* __restrict__ partials, const float* __restrict__ flags,
    const float* __restrict__ vw, const float* __restrict__ vb,
    float* __restrict__ rep)
{
    const int b = blockIdx.x;
    const int t = threadIdx.x;      // 256 = R (and D for the reduce)
    __shared__ float sv[SD];
    float a = 0.f;
    for (int c = 0; c < 64; ++c) a += partials[((size_t)b * 64 + c) * SD + t];
    sv[t] = a;
    __syncthreads();
    const float f = flags[b];
    float r = vb[t] * f;
    for (int dd = 0; dd < SD; ++dd) r = fmaf(sv[dd], vw[(size_t)dd * 256 + t], r);
    rep[(size_t)b * 256 + t] = r;
}

// ---------------------------------------------------------------------------
extern "C" void kernel_launch(void* const* d_in, const int* in_sizes, int n_in,
                              void* d_out, int out_size, void* d_ws, size_t ws_size,
                              hipStream_t stream)
{
    const float* x     = (const float*)d_in[0];
    const int*   mask  = (const int*)  d_in[1];
    const float* gamma = (const float*)d_in[2];
    const float* beta  = (const float*)d_in[3];
    const float* dw1   = (const float*)d_in[4];
    const float* db1   = (const float*)d_in[5];
    const float* dw2   = (const float*)d_in[6];
    const float* db2   = (const float*)d_in[7];
    const float* rw1   = (const float*)d_in[8];
    const float* rb1   = (const float*)d_in[9];
    const float* rw2   = (const float*)d_in[10];
    const float* rb2   = (const float*)d_in[11];
    const float* vw    = (const float*)d_in[12];
    const float* vb    = (const float*)d_in[13];

    float* out     = (float*)d_out;
    float* rep     = out;                       // 32*256      = 8192
    float* weights = out + 8192;                // 32*8192     = 262144
    float* ti      = out + 8192 + 262144;       // 32*3        = 96
    float* tw      = ti + 96;                   // 32*3        = 96
    float* logits  = tw + 96;                   // 32*8192     = 262144

    float* ws       = (float*)d_ws;
    float* murstd   = ws;                       // 2*262144 floats = 2 MB
    float* partials = ws + 524288;              // 32*64*256 floats = 2 MB
    float* flags    = ws + 1048576;             // 32 floats

    hipLaunchKernelGGL(k_logits, dim3(4096), dim3(256), 0, stream,
                       x, gamma, beta, dw1, db1, dw2, db2, rw1, rb1, rw2, rb2,
                       logits, murstd);
    hipLaunchKernelGGL(k_softmax_topk, dim3(32), dim3(256), 0, stream,
                       logits, mask, weights, ti, tw, flags);
    hipLaunchKernelGGL(k_wsum, dim3(64, 32), dim3(256), 0, stream,
                       x, weights, murstd, gamma, beta, partials);
    hipLaunchKernelGGL(k_final, dim3(32), dim3(256), 0, stream,
                       partials, flags, vw, vb, rep);
}